// Round 5
// baseline (141.957 us; speedup 1.0000x reference)
//
#include <hip/hip_runtime.h>
#include <math.h>

// EUNN layer, H=1024: 16 steps of (even + odd) pairwise complex rotations + final phase.
// v5 = v4 + LDS coefficient staging. In v4 each of the 8 waves/CU redundantly
// pulled the same 256 KB coeff stream through the L1 return path (16 lines per
// dwordx4). v5 stages each step's 16 KB coeff block ONCE per block into LDS via
// __builtin_amdgcn_global_load_lds (width 16, double-buffered), and waves read
// fragments with conflict-free lane-contiguous ds_read_b128.
//
// ws layout (f4 units): coeff_t[s][phase][512], slot k = (j&7)*64 + (j>>3) for pair j
//   (phase 0 = even pairs 0..511; phase 1 = odd pairs 0..510 + identity pad 511)
// omega (f4 = 2 elements (c,s,c,s)) transposed the same way at float offset 65536.

typedef float f4 __attribute__((ext_vector_type(4)));

#define OMCS_OFF 65536

__global__ __launch_bounds__(256) void eunn_precompute(
    const float* __restrict__ omega, const float* __restrict__ et,
    const float* __restrict__ ot, const float* __restrict__ ep,
    const float* __restrict__ op, float* __restrict__ ws) {
  int tid = blockIdx.x * 256 + threadIdx.x;
  if (tid < 16384) {
    int s = tid >> 10, k = tid & 1023;
    int phase = k >> 9, j = k & 511;
    float ct, st, cp, sp;
    if (phase == 0) {
      sincosf(et[s * 512 + j], &st, &ct);
      sincosf(ep[s * 512 + j], &sp, &cp);
    } else if (j < 511) {
      sincosf(ot[s * 511 + j], &st, &ct);
      sincosf(op[s * 511 + j], &sp, &cp);
    } else {  // identity pad pair (elements 1023/1024)
      ct = 1.f; st = 0.f; cp = 0.f; sp = 1.f;
    }
    // transposed slot: lane = j>>3 owns pair j as its (j&7)-th register
    ((f4*)ws)[s * 1024 + phase * 512 + (j & 7) * 64 + (j >> 3)] =
        (f4){ct, st, cp, sp};
  } else if (tid < 16896) {
    int m = tid - 16384;  // f4 index covering elements 2m, 2m+1
    float s0, c0, s1, c1;
    sincosf(omega[2 * m], &s0, &c0);
    sincosf(omega[2 * m + 1], &s1, &c1);
    ((f4*)(ws + OMCS_OFF))[(m & 7) * 64 + (m >> 3)] = (f4){c0, s0, c1, s1};
  }
}

// One wave owns R rows; lane l owns elements 16l..16l+15 (8 even pairs).
// Even rotations register-local; odd rotations register-local except one
// boundary pair per lane (intra-wave shfl). Coeffs staged to LDS per block,
// double-buffered: stage(s+1) issues right after the step-s barrier and has a
// full step of compute to complete before the barrier that consumes it.
template <int R>
__global__ __launch_bounds__(256, 2) void eunn_main(
    const float* __restrict__ x, float* __restrict__ out,
    const float* __restrict__ ws) {
  const int lane = threadIdx.x & 63;
  const int wave = threadIdx.x >> 6;
  const int wid = blockIdx.x * 4 + wave;

  __shared__ f4 sbuf[2][1024];  // 2 x 16 KB coeff step-blocks

  // stage one 16 KB step-block: linear copy, wave w moves its 4 KB quarter
  auto stage = [&](int s2, f4* dst) {
    const float* g = ws + s2 * 4096 + wave * 1024 + lane * 4;
    char* lbase = (char*)dst + wave * 4096;
#pragma unroll
    for (int c = 0; c < 4; ++c) {
      __builtin_amdgcn_global_load_lds(
          (const __attribute__((address_space(1))) void*)(g + c * 256),
          (__attribute__((address_space(3))) void*)(lbase + c * 1024),
          16, 0, 0);
    }
  };

  // e[r][p] = (re[16l+2p], im[16l+2p], re[16l+2p+1], im[16l+2p+1])
  f4 e[R][8];
#pragma unroll
  for (int r = 0; r < R; ++r) {
    const f4* xr = (const f4*)(x + (size_t)(wid * R + r) * 2048) + lane * 8;
#pragma unroll
    for (int p = 0; p < 8; ++p) e[r][p] = xr[p];
  }

  f4* rd = sbuf[0];
  f4* wr = sbuf[1];
  stage(0, rd);

#pragma unroll 1
  for (int s = 0; s < 16; ++s) {
    __syncthreads();  // staging of step s complete; prev reads of wr done
    if (s < 15) stage(s + 1, wr);
    // ---- even coeffs from LDS: E[p] = pair 8*lane+p ----
    f4 E[8];
#pragma unroll
    for (int p = 0; p < 8; ++p) E[p] = rd[p * 64 + lane];
    // ---- even rotation: pair j=8l+p couples (e.x,e.y) and (e.z,e.w) ----
#pragma unroll
    for (int r = 0; r < R; ++r) {
#pragma unroll
      for (int p = 0; p < 8; ++p) {
        f4 c = E[p];
        f4 v = e[r][p];
        float t0 = c.x * v.x - c.y * v.z;
        float t1 = c.x * v.y - c.y * v.w;
        e[r][p] = (f4){c.w * t0 - c.z * t1, c.z * t0 + c.w * t1,
                       c.y * v.x + c.x * v.z, c.y * v.y + c.x * v.w};
      }
    }
    // ---- odd coeffs from LDS ----
    f4 O[8];
#pragma unroll
    for (int p = 0; p < 8; ++p) O[p] = rd[512 + p * 64 + lane];
    // ---- odd rotation: pair j couples elements 2j+1, 2j+2 ----
    {
      // neighbor pair (8l-1)'s (ct,st) from lane l-1; identity at lane 0
      float ctm = __shfl_up(O[7].x, 1, 64);
      float stm = __shfl_up(O[7].y, 1, 64);
      if (lane == 0) { ctm = 1.f; stm = 0.f; }
#pragma unroll
      for (int r = 0; r < R; ++r) {
        float upx = __shfl_down(e[r][0].x, 1, 64);  // elem 16l+16 (pre)
        float upy = __shfl_down(e[r][0].y, 1, 64);
        float dnz = __shfl_up(e[r][7].z, 1, 64);    // elem 16l-1 (pre)
        float dnw = __shfl_up(e[r][7].w, 1, 64);
        // element 16l = second half of pair 8l-1
        float nx = stm * dnz + ctm * e[r][0].x;
        float ny = stm * dnw + ctm * e[r][0].y;
        e[r][0].x = nx;
        e[r][0].y = ny;
        // interior odd pairs j=8l+p, p=0..6
#pragma unroll
        for (int p = 0; p < 7; ++p) {
          f4 c = O[p];
          float e0r = e[r][p].z, e0i = e[r][p].w;
          float e1r = e[r][p + 1].x, e1i = e[r][p + 1].y;
          float t0 = c.x * e0r - c.y * e1r;
          float t1 = c.x * e0i - c.y * e1i;
          e[r][p].z = c.w * t0 - c.z * t1;
          e[r][p].w = c.z * t0 + c.w * t1;
          e[r][p + 1].x = c.y * e0r + c.x * e1r;
          e[r][p + 1].y = c.y * e0i + c.x * e1i;
        }
        // boundary pair j=8l+7 (second element lives in lane l+1; lane 63 = identity)
        {
          f4 c = O[7];
          float e0r = e[r][7].z, e0i = e[r][7].w;
          float t0 = c.x * e0r - c.y * upx;
          float t1 = c.x * e0i - c.y * upy;
          e[r][7].z = c.w * t0 - c.z * t1;
          e[r][7].w = c.z * t0 + c.w * t1;
        }
      }
    }
    // swap buffers
    f4* t = rd; rd = wr; wr = t;
  }

  // ---- final diagonal phase + store ----
  const f4* om4 = (const f4*)(ws + OMCS_OFF) + lane;  // (c,s,c,s), + p*64
#pragma unroll
  for (int r = 0; r < R; ++r) {
    f4* outr = (f4*)(out + (size_t)(wid * R + r) * 2048) + lane * 8;
#pragma unroll
    for (int p = 0; p < 8; ++p) {
      f4 v = e[r][p];
      f4 w = om4[p * 64];
      outr[p] = (f4){v.x * w.x - v.y * w.y, v.x * w.y + v.y * w.x,
                     v.z * w.z - v.w * w.w, v.z * w.w + v.w * w.z};
    }
  }
}

extern "C" void kernel_launch(void* const* d_in, const int* in_sizes, int n_in,
                              void* d_out, int out_size, void* d_ws, size_t ws_size,
                              hipStream_t stream) {
  const float* x     = (const float*)d_in[0];  // (4096,1024,2)
  const float* omega = (const float*)d_in[1];  // (1024,)
  const float* et    = (const float*)d_in[2];  // (16,512)
  const float* ot    = (const float*)d_in[3];  // (16,511)
  const float* ep    = (const float*)d_in[4];  // (16,512)
  const float* op    = (const float*)d_in[5];  // (16,511)
  float* out = (float*)d_out;
  float* ws  = (float*)d_ws;

  // 16896 jobs: 16x1024 coeff quads + 512 omega f4 entries
  eunn_precompute<<<dim3(66), dim3(256), 0, stream>>>(omega, et, ot, ep, op, ws);

  // R=2 rows/wave: 2048 waves, 4 waves/block -> 512 blocks
  eunn_main<2><<<dim3(512), dim3(256), 0, stream>>>(x, out, ws);
}

// Round 6
// 134.465 us; speedup vs baseline: 1.0557x; 1.0557x over previous
//
#include <hip/hip_runtime.h>
#include <math.h>

// EUNN layer, H=1024: 16 steps of (even + odd) pairwise complex rotations + final phase.
// v6 = v4 structure (register pipeline, transposed coeff layout, NO LDS staging)
// with two changes targeting the diagnosed latency-bound stall (v4: 59us, VALU 23us,
// ~36us non-overlapped mem with only 2 waves/SIMD):
//   1. R=1 row/wave -> 4096 waves = 4 waves/SIMD (2x TLP).
//   2. f16-packed coeffs (8 B/pair): coeff loads dwordx2 -> 8 lines/instr (2x fewer),
//      consumed via (float)h casts that fold into v_fma_mix_f32 (f32 accumulate).
// Precision: f16 coeff err 5e-4 * sqrt(32 steps) * |x|~5 ~= 0.015 added absmax; thr 0.104.
//
// ws layout: h4 coeff_t[16][2][512] (8B each), slot k = (j&7)*64 + (j>>3) for pair j
//   (phase 0 = even pairs 0..511; phase 1 = odd pairs 0..510 + identity pad 511)
// omega: f4 (c,s,c,s) per 2 elements, transposed the same way, at float offset 32768.

typedef float f4 __attribute__((ext_vector_type(4)));
typedef _Float16 h4 __attribute__((ext_vector_type(4)));

#define OMCS_OFF 32768

__global__ __launch_bounds__(256) void eunn_precompute(
    const float* __restrict__ omega, const float* __restrict__ et,
    const float* __restrict__ ot, const float* __restrict__ ep,
    const float* __restrict__ op, float* __restrict__ ws) {
  int tid = blockIdx.x * 256 + threadIdx.x;
  if (tid < 16384) {
    int s = tid >> 10, k = tid & 1023;
    int phase = k >> 9, j = k & 511;
    float ct, st, cp, sp;
    if (phase == 0) {
      sincosf(et[s * 512 + j], &st, &ct);
      sincosf(ep[s * 512 + j], &sp, &cp);
    } else if (j < 511) {
      sincosf(ot[s * 511 + j], &st, &ct);
      sincosf(op[s * 511 + j], &sp, &cp);
    } else {  // identity pad pair (elements 1023/1024)
      ct = 1.f; st = 0.f; cp = 0.f; sp = 1.f;
    }
    // transposed slot: lane = j>>3 owns pair j as its (j&7)-th register
    ((h4*)ws)[s * 1024 + phase * 512 + (j & 7) * 64 + (j >> 3)] =
        (h4){(_Float16)ct, (_Float16)st, (_Float16)cp, (_Float16)sp};
  } else if (tid < 16896) {
    int m = tid - 16384;  // f4 index covering elements 2m, 2m+1
    float s0, c0, s1, c1;
    sincosf(omega[2 * m], &s0, &c0);
    sincosf(omega[2 * m + 1], &s1, &c1);
    ((f4*)(ws + OMCS_OFF))[(m & 7) * 64 + (m >> 3)] = (f4){c0, s0, c1, s1};
  }
}

// One wave owns ONE row; lane l owns elements 16l..16l+15 (8 even pairs).
// Even rotations register-local; odd rotations register-local except one
// boundary pair per lane (intra-wave shfl). Pipeline: O loads issue before
// even compute; next step's E loads issue after even compute.
__global__ __launch_bounds__(256, 4) void eunn_main(
    const float* __restrict__ x, float* __restrict__ out,
    const float* __restrict__ ws) {
  const int lane = threadIdx.x & 63;
  const int wid = blockIdx.x * 4 + (threadIdx.x >> 6);
  const h4* cf = (const h4*)ws + lane;  // + p*64 + s*1024 (+512 for odd)

  // e[p] = (re[16l+2p], im[16l+2p], re[16l+2p+1], im[16l+2p+1])
  f4 e[8];
  {
    const f4* xr = (const f4*)(x + (size_t)wid * 2048) + lane * 8;
#pragma unroll
    for (int p = 0; p < 8; ++p) e[p] = xr[p];
  }

  h4 E[8];  // current step's even coeffs (ct,st,cp,sp per pair)
#pragma unroll
  for (int p = 0; p < 8; ++p) E[p] = cf[p * 64];

#pragma unroll 1
  for (int s = 0; s < 16; ++s) {
    // ---- issue odd coeff loads (completion covered by even compute) ----
    h4 O[8];
    {
      const h4* ob = cf + s * 1024 + 512;
#pragma unroll
      for (int p = 0; p < 8; ++p) O[p] = ob[p * 64];
    }
    // ---- even rotation: pair j=8l+p couples (e.x,e.y) and (e.z,e.w) ----
#pragma unroll
    for (int p = 0; p < 8; ++p) {
      h4 c = E[p];
      float cx = (float)c.x, cy = (float)c.y, cz = (float)c.z, cw = (float)c.w;
      f4 v = e[p];
      float t0 = cx * v.x - cy * v.z;
      float t1 = cx * v.y - cy * v.w;
      e[p] = (f4){cw * t0 - cz * t1, cz * t0 + cw * t1,
                  cy * v.x + cx * v.z, cy * v.y + cx * v.w};
    }
    // ---- load next step's even coeffs into E (covered by odd compute) ----
    {
      const h4* nb = cf + ((s + 1) & 15) * 1024;
#pragma unroll
      for (int p = 0; p < 8; ++p) E[p] = nb[p * 64];
    }
    // ---- odd rotation: pair j couples elements 2j+1, 2j+2 ----
    {
      // neighbor pair (8l-1)'s (ct,st) from lane l-1; identity at lane 0
      float ctm = __shfl_up((float)O[7].x, 1, 64);
      float stm = __shfl_up((float)O[7].y, 1, 64);
      if (lane == 0) { ctm = 1.f; stm = 0.f; }
      float upx = __shfl_down(e[0].x, 1, 64);  // elem 16l+16 (pre)
      float upy = __shfl_down(e[0].y, 1, 64);
      float dnz = __shfl_up(e[7].z, 1, 64);    // elem 16l-1 (pre)
      float dnw = __shfl_up(e[7].w, 1, 64);
      // element 16l = second half of pair 8l-1
      float nx = stm * dnz + ctm * e[0].x;
      float ny = stm * dnw + ctm * e[0].y;
      e[0].x = nx;
      e[0].y = ny;
      // interior odd pairs j=8l+p, p=0..6
#pragma unroll
      for (int p = 0; p < 7; ++p) {
        h4 c = O[p];
        float cx = (float)c.x, cy = (float)c.y, cz = (float)c.z, cw = (float)c.w;
        float e0r = e[p].z, e0i = e[p].w;
        float e1r = e[p + 1].x, e1i = e[p + 1].y;
        float t0 = cx * e0r - cy * e1r;
        float t1 = cx * e0i - cy * e1i;
        e[p].z = cw * t0 - cz * t1;
        e[p].w = cz * t0 + cw * t1;
        e[p + 1].x = cy * e0r + cx * e1r;
        e[p + 1].y = cy * e0i + cx * e1i;
      }
      // boundary pair j=8l+7 (second element lives in lane l+1; lane 63 = identity)
      {
        h4 c = O[7];
        float cx = (float)c.x, cy = (float)c.y, cz = (float)c.z, cw = (float)c.w;
        float e0r = e[7].z, e0i = e[7].w;
        float t0 = cx * e0r - cy * upx;
        float t1 = cx * e0i - cy * upy;
        e[7].z = cw * t0 - cz * t1;
        e[7].w = cz * t0 + cw * t1;
      }
    }
  }

  // ---- final diagonal phase + store ----
  const f4* om4 = (const f4*)(ws + OMCS_OFF) + lane;  // (c,s,c,s), + p*64
  {
    f4* outr = (f4*)(out + (size_t)wid * 2048) + lane * 8;
#pragma unroll
    for (int p = 0; p < 8; ++p) {
      f4 v = e[p];
      f4 w = om4[p * 64];
      outr[p] = (f4){v.x * w.x - v.y * w.y, v.x * w.y + v.y * w.x,
                     v.z * w.z - v.w * w.w, v.z * w.w + v.w * w.z};
    }
  }
}

extern "C" void kernel_launch(void* const* d_in, const int* in_sizes, int n_in,
                              void* d_out, int out_size, void* d_ws, size_t ws_size,
                              hipStream_t stream) {
  const float* x     = (const float*)d_in[0];  // (4096,1024,2)
  const float* omega = (const float*)d_in[1];  // (1024,)
  const float* et    = (const float*)d_in[2];  // (16,512)
  const float* ot    = (const float*)d_in[3];  // (16,511)
  const float* ep    = (const float*)d_in[4];  // (16,512)
  const float* op    = (const float*)d_in[5];  // (16,511)
  float* out = (float*)d_out;
  float* ws  = (float*)d_ws;

  // 16896 jobs: 16x1024 coeff quads + 512 omega f4 entries
  eunn_precompute<<<dim3(66), dim3(256), 0, stream>>>(omega, et, ot, ep, op, ws);

  // 1 row/wave: 4096 waves, 4 waves/block -> 1024 blocks, 4 waves/SIMD
  eunn_main<<<dim3(1024), dim3(256), 0, stream>>>(x, out, ws);
}

// Round 7
// 133.547 us; speedup vs baseline: 1.0630x; 1.0069x over previous
//
#include <hip/hip_runtime.h>
#include <math.h>

// EUNN layer, H=1024: 16 steps of (even + odd) pairwise complex rotations + final phase.
// v7 = v6 math (f16 coeffs, 1 row/wave, register-held state) but coeffs are
// staged into LDS (64 KB = 8 steps per stage, 2 stages) via global_load_lds,
// so the steady-state step loop has ZERO global memory ops: ds_read_b64 + VALU.
// 512-thread blocks, 2 blocks/CU, 16 waves/CU = 4 waves/SIMD.
//
// ws layout: h4 coeff_t[16][2][512] (8B each), slot k = (j&7)*64 + (j>>3) for pair j
//   (phase 0 = even pairs 0..511; phase 1 = odd pairs 0..510 + identity pad 511)
// omega: f4 (c,s,c,s) per 2 elements, transposed the same way, at float offset 32768.

typedef float f4 __attribute__((ext_vector_type(4)));
typedef _Float16 h4 __attribute__((ext_vector_type(4)));

#define OMCS_OFF 32768

__global__ __launch_bounds__(256) void eunn_precompute(
    const float* __restrict__ omega, const float* __restrict__ et,
    const float* __restrict__ ot, const float* __restrict__ ep,
    const float* __restrict__ op, float* __restrict__ ws) {
  int tid = blockIdx.x * 256 + threadIdx.x;
  if (tid < 16384) {
    int s = tid >> 10, k = tid & 1023;
    int phase = k >> 9, j = k & 511;
    float ct, st, cp, sp;
    if (phase == 0) {
      sincosf(et[s * 512 + j], &st, &ct);
      sincosf(ep[s * 512 + j], &sp, &cp);
    } else if (j < 511) {
      sincosf(ot[s * 511 + j], &st, &ct);
      sincosf(op[s * 511 + j], &sp, &cp);
    } else {  // identity pad pair (elements 1023/1024)
      ct = 1.f; st = 0.f; cp = 0.f; sp = 1.f;
    }
    // transposed slot: lane = j>>3 owns pair j as its (j&7)-th register
    ((h4*)ws)[s * 1024 + phase * 512 + (j & 7) * 64 + (j >> 3)] =
        (h4){(_Float16)ct, (_Float16)st, (_Float16)cp, (_Float16)sp};
  } else if (tid < 16896) {
    int m = tid - 16384;  // f4 index covering elements 2m, 2m+1
    float s0, c0, s1, c1;
    sincosf(omega[2 * m], &s0, &c0);
    sincosf(omega[2 * m + 1], &s1, &c1);
    ((f4*)(ws + OMCS_OFF))[(m & 7) * 64 + (m >> 3)] = (f4){c0, s0, c1, s1};
  }
}

// One wave owns ONE row; lane l owns elements 16l..16l+15 (8 even pairs).
// Even rotations register-local; odd rotations register-local except one
// boundary pair per lane (intra-wave shfl).
__global__ __launch_bounds__(512, 4) void eunn_main(
    const float* __restrict__ x, float* __restrict__ out,
    const float* __restrict__ ws) {
  const int lane = threadIdx.x & 63;
  const int wid = blockIdx.x * 8 + (threadIdx.x >> 6);

  __shared__ __attribute__((aligned(16))) char lds[65536];  // 8 steps of coeffs

  // ---- stage steps 0..7 (64 KB): 512 threads x 16 B x 8 iters ----
  {
    const char* g = (const char*)ws + threadIdx.x * 16;
#pragma unroll
    for (int i = 0; i < 8; ++i) {
      __builtin_amdgcn_global_load_lds(
          (const __attribute__((address_space(1))) void*)(g + i * 8192),
          (__attribute__((address_space(3))) void*)(lds + i * 8192 +
                                                    threadIdx.x * 16),
          16, 0, 0);
    }
  }

  // e[p] = (re[16l+2p], im[16l+2p], re[16l+2p+1], im[16l+2p+1])
  f4 e[8];
  {
    const f4* xr = (const f4*)(x + (size_t)wid * 2048) + lane * 8;
#pragma unroll
    for (int p = 0; p < 8; ++p) e[p] = xr[p];
  }

  __syncthreads();  // staging of steps 0..7 complete (vmcnt drained at barrier)

#pragma unroll 1
  for (int half = 0; half < 2; ++half) {
    if (half == 1) {
      __syncthreads();  // everyone done reading steps 0..7
      const char* g = (const char*)ws + 65536 + threadIdx.x * 16;
#pragma unroll
      for (int i = 0; i < 8; ++i) {
        __builtin_amdgcn_global_load_lds(
            (const __attribute__((address_space(1))) void*)(g + i * 8192),
            (__attribute__((address_space(3))) void*)(lds + i * 8192 +
                                                      threadIdx.x * 16),
            16, 0, 0);
      }
      __syncthreads();  // staging of steps 8..15 complete
    }
#pragma unroll 1
    for (int s = 0; s < 8; ++s) {
      const h4* L = (const h4*)lds + s * 1024 + lane;
      // ---- coeffs from LDS: lane-contiguous ds_read_b64, conflict-light ----
      h4 E[8], O[8];
#pragma unroll
      for (int p = 0; p < 8; ++p) E[p] = L[p * 64];
#pragma unroll
      for (int p = 0; p < 8; ++p) O[p] = L[512 + p * 64];
      // ---- even rotation: pair j=8l+p couples (e.x,e.y) and (e.z,e.w) ----
#pragma unroll
      for (int p = 0; p < 8; ++p) {
        h4 c = E[p];
        float cx = (float)c.x, cy = (float)c.y, cz = (float)c.z,
              cw = (float)c.w;
        f4 v = e[p];
        float t0 = cx * v.x - cy * v.z;
        float t1 = cx * v.y - cy * v.w;
        e[p] = (f4){cw * t0 - cz * t1, cz * t0 + cw * t1,
                    cy * v.x + cx * v.z, cy * v.y + cx * v.w};
      }
      // ---- odd rotation: pair j couples elements 2j+1, 2j+2 ----
      {
        // neighbor pair (8l-1)'s (ct,st) from lane l-1; identity at lane 0
        float ctm = __shfl_up((float)O[7].x, 1, 64);
        float stm = __shfl_up((float)O[7].y, 1, 64);
        if (lane == 0) { ctm = 1.f; stm = 0.f; }
        float upx = __shfl_down(e[0].x, 1, 64);  // elem 16l+16 (pre)
        float upy = __shfl_down(e[0].y, 1, 64);
        float dnz = __shfl_up(e[7].z, 1, 64);    // elem 16l-1 (pre)
        float dnw = __shfl_up(e[7].w, 1, 64);
        // element 16l = second half of pair 8l-1
        float nx = stm * dnz + ctm * e[0].x;
        float ny = stm * dnw + ctm * e[0].y;
        e[0].x = nx;
        e[0].y = ny;
        // interior odd pairs j=8l+p, p=0..6
#pragma unroll
        for (int p = 0; p < 7; ++p) {
          h4 c = O[p];
          float cx = (float)c.x, cy = (float)c.y, cz = (float)c.z,
                cw = (float)c.w;
          float e0r = e[p].z, e0i = e[p].w;
          float e1r = e[p + 1].x, e1i = e[p + 1].y;
          float t0 = cx * e0r - cy * e1r;
          float t1 = cx * e0i - cy * e1i;
          e[p].z = cw * t0 - cz * t1;
          e[p].w = cz * t0 + cw * t1;
          e[p + 1].x = cy * e0r + cx * e1r;
          e[p + 1].y = cy * e0i + cx * e1i;
        }
        // boundary pair j=8l+7 (second element in lane l+1; lane 63 = identity)
        {
          h4 c = O[7];
          float cx = (float)c.x, cy = (float)c.y, cz = (float)c.z,
                cw = (float)c.w;
          float e0r = e[7].z, e0i = e[7].w;
          float t0 = cx * e0r - cy * upx;
          float t1 = cx * e0i - cy * upy;
          e[7].z = cw * t0 - cz * t1;
          e[7].w = cz * t0 + cw * t1;
        }
      }
    }
  }

  // ---- final diagonal phase + store ----
  const f4* om4 = (const f4*)(ws + OMCS_OFF) + lane;  // (c,s,c,s), + p*64
  {
    f4* outr = (f4*)(out + (size_t)wid * 2048) + lane * 8;
#pragma unroll
    for (int p = 0; p < 8; ++p) {
      f4 v = e[p];
      f4 w = om4[p * 64];
      outr[p] = (f4){v.x * w.x - v.y * w.y, v.x * w.y + v.y * w.x,
                     v.z * w.z - v.w * w.w, v.z * w.w + v.w * w.z};
    }
  }
}

extern "C" void kernel_launch(void* const* d_in, const int* in_sizes, int n_in,
                              void* d_out, int out_size, void* d_ws, size_t ws_size,
                              hipStream_t stream) {
  const float* x     = (const float*)d_in[0];  // (4096,1024,2)
  const float* omega = (const float*)d_in[1];  // (1024,)
  const float* et    = (const float*)d_in[2];  // (16,512)
  const float* ot    = (const float*)d_in[3];  // (16,511)
  const float* ep    = (const float*)d_in[4];  // (16,512)
  const float* op    = (const float*)d_in[5];  // (16,511)
  float* out = (float*)d_out;
  float* ws  = (float*)d_ws;

  // 16896 jobs: 16x1024 coeff quads + 512 omega f4 entries
  eunn_precompute<<<dim3(66), dim3(256), 0, stream>>>(omega, et, ot, ep, op, ws);

  // 1 row/wave: 4096 waves, 8 waves/block -> 512 blocks, 2 blocks/CU, 4 waves/SIMD
  eunn_main<<<dim3(512), dim3(512), 0, stream>>>(x, out, ws);
}